// Round 3
// baseline (509.930 us; speedup 1.0000x reference)
//
#include <hip/hip_runtime.h>
#include <hip/hip_bf16.h>

// Problem constants
#define ROWS  4096      // B*T
#define DDIM  1024
#define DKDIM 256
#define NKEYS 32768
#define DMDIM 256
#define KN    8
#define FDIM  2048      // KN*DM
#define CAPS  1536      // pushed-candidate cap per row
#define SURV  128       // survivors after exact-max filter (typical 2-10)
#define MARGIN 16.0f    // s-units; required bound ~12.8 incl bf16 err

typedef float  f32x4  __attribute__((ext_vector_type(4)));
typedef __bf16 bf16x8 __attribute__((ext_vector_type(8)));

static __device__ __forceinline__ unsigned enc_f32(float f) {
  unsigned u = __float_as_uint(f);
  return u ^ ((unsigned)((int)u >> 31) | 0x80000000u);
}
static __device__ __forceinline__ float dec_f32(unsigned u) {
  unsigned b = (u & 0x80000000u) ? (u ^ 0x80000000u) : ~u;
  return __uint_as_float(b);
}
static __device__ __forceinline__ unsigned short f2bf(float f) {
  unsigned u = __float_as_uint(f);
  u += 0x7FFFu + ((u >> 16) & 1u);          // RNE truncate to bf16
  return (unsigned short)(u >> 16);
}
// pack candidate: score quantized to 17 bits in high bits, key id (15 bits) low.
static __device__ __forceinline__ unsigned pack_cand(float s, int n) {
  float q = (s + 1024.f) * 64.f;
  int u = (int)q;
  u = u < 0 ? 0 : (u > 131071 ? 131071 : u);
  return ((unsigned)u << 15) | (unsigned)n;
}
static __device__ __forceinline__ float cand_score(unsigned p) {
  return (float)(p >> 15) * (1.f / 64.f) - 1024.f;
}
static __device__ __forceinline__ void gld16(const void* g, void* l) {
  __builtin_amdgcn_global_load_lds((const __attribute__((address_space(1))) void*)g,
                                   (__attribute__((address_space(3))) void*)l, 16, 0, 0);
}

// ---------------------------------------------------------------- prep keys
__global__ __launch_bounds__(256) void prep_keys(const float* __restrict__ keys,
                                                 unsigned short* __restrict__ kbf,
                                                 float* __restrict__ k2) {
  const int row = blockIdx.x * 4 + (threadIdx.x >> 6);
  const int ln  = threadIdx.x & 63;
  const float4 v = *(const float4*)(keys + (size_t)row * DKDIM + ln * 4);
  ushort4 o;
  o.x = f2bf(v.x); o.y = f2bf(v.y); o.z = f2bf(v.z); o.w = f2bf(v.w);
  *(ushort4*)(kbf + (size_t)row * DKDIM + ln * 4) = o;
  float ss = v.x*v.x + v.y*v.y + v.z*v.z + v.w*v.w;
  for (int off = 32; off; off >>= 1) ss += __shfl_down(ss, off);
  if (ln == 0) k2[row] = ss;
}

// ---------------------------------------------------------------- fp32 -> bf16
__global__ __launch_bounds__(256) void cvt_bf16(const float* __restrict__ src,
                                                unsigned short* __restrict__ dst, int n4) {
  const int i = blockIdx.x * 256 + threadIdx.x;
  if (i < n4) {
    const float4 v = *(const float4*)(src + (size_t)i * 4);
    ushort4 o;
    o.x = f2bf(v.x); o.y = f2bf(v.y); o.z = f2bf(v.z); o.w = f2bf(v.w);
    *(ushort4*)(dst + (size_t)i * 4) = o;
  }
}

// ---------------------------------------------------------------- q = x @ W_in^T + b_in (fp32)
__global__ __launch_bounds__(256) void qproj(const float* __restrict__ x,
                                             const float* __restrict__ Win,
                                             const float* __restrict__ bin,
                                             float* __restrict__ qf,
                                             unsigned short* __restrict__ qbf) {
  __shared__ __align__(16) float As[64][68];
  __shared__ __align__(16) float Bs[64][68];
  const int bm = blockIdx.x, bn = blockIdx.y;
  const int t  = threadIdx.x;
  const int tx = t & 15, ty = t >> 4;
  float acc[4][4] = {};
  for (int ks = 0; ks < 16; ++ks) {
    __syncthreads();
    for (int l = t; l < 1024; l += 256) {
      const int row = l >> 4, kc = l & 15;
      *(float4*)(&As[row][kc * 4]) =
          *(const float4*)(x + (size_t)(bm * 64 + row) * DDIM + ks * 64 + kc * 4);
      *(float4*)(&Bs[row][kc * 4]) =
          *(const float4*)(Win + (size_t)(bn * 64 + row) * DDIM + ks * 64 + kc * 4);
    }
    __syncthreads();
    for (int kk = 0; kk < 64; kk += 4) {
      float4 av[4], bv[4];
#pragma unroll
      for (int i = 0; i < 4; ++i) av[i] = *(const float4*)(&As[ty * 4 + i][kk]);
#pragma unroll
      for (int j = 0; j < 4; ++j) bv[j] = *(const float4*)(&Bs[tx * 4 + j][kk]);
#pragma unroll
      for (int i = 0; i < 4; ++i)
#pragma unroll
        for (int j = 0; j < 4; ++j)
          acc[i][j] += av[i].x * bv[j].x + av[i].y * bv[j].y +
                       av[i].z * bv[j].z + av[i].w * bv[j].w;
    }
  }
#pragma unroll
  for (int i = 0; i < 4; ++i)
#pragma unroll
    for (int j = 0; j < 4; ++j) {
      const int m = bm * 64 + ty * 4 + i, n = bn * 64 + tx * 4 + j;
      const float q = acc[i][j] + bin[n];
      qf[(size_t)m * DKDIM + n] = q;
      qbf[(size_t)m * DKDIM + n] = f2bf(q);
    }
}

// ---------------------------------------------------------------- shared MFMA tile (m97 structure)
template <int KD>
static __device__ __forceinline__ void gemm_tile(const unsigned short* __restrict__ A,
                                                 const unsigned short* __restrict__ B,
                                                 int bm, int bn,
                                                 unsigned short* As, unsigned short* Bs,
                                                 f32x4 acc[4][4]) {
  const int tid  = threadIdx.x;
  const int lane = tid & 63, wave = tid >> 6;
  const int quad = lane >> 4, l15 = lane & 15;
  const int wr = (wave >> 1) * 64, wc = (wave & 1) * 64;
  const int srow = tid >> 2, skc = tid & 3;
  const unsigned short* gA = A + (size_t)(bm * 128 + srow) * KD + skc * 8;
  const unsigned short* gB = B + (size_t)(bn * 128 + srow) * KD + skc * 8;
  for (int ks = 0; ks < KD / 32; ++ks) {
    __syncthreads();
    gld16(gA + ks * 32,                     As + tid * 8);
    gld16(gA + (size_t)64 * KD + ks * 32,   As + 2048 + tid * 8);
    gld16(gB + ks * 32,                     Bs + tid * 8);
    gld16(gB + (size_t)64 * KD + ks * 32,   Bs + 2048 + tid * 8);
    __syncthreads();
    bf16x8 af[4], bfr[4];
#pragma unroll
    for (int i = 0; i < 4; ++i)
      af[i] = *(const bf16x8*)(As + (wr + i * 16 + l15) * 32 + quad * 8);
#pragma unroll
    for (int j = 0; j < 4; ++j)
      bfr[j] = *(const bf16x8*)(Bs + (wc + j * 16 + l15) * 32 + quad * 8);
#pragma unroll
    for (int i = 0; i < 4; ++i)
#pragma unroll
      for (int j = 0; j < 4; ++j)
        acc[i][j] = __builtin_amdgcn_mfma_f32_16x16x32_bf16(af[i], bfr[j], acc[i][j], 0, 0, 0);
  }
}

// ---------------------------------------------------------------- seed: row max over first 2048 keys
// Gives every row a guaranteed lower bound of the global max before score_strip.
__global__ __launch_bounds__(256) void seed_max(const unsigned short* __restrict__ qbf,
                                                const unsigned short* __restrict__ kbf,
                                                const float* __restrict__ k2,
                                                unsigned* __restrict__ rowmax) {
  __shared__ __align__(16) unsigned short As[4096];
  __shared__ __align__(16) unsigned short Bs[4096];
  f32x4 acc[4][4] = {};
  gemm_tile<DKDIM>(qbf, kbf, blockIdx.x, blockIdx.y, As, Bs, acc);
  const int lane = threadIdx.x & 63, wave = threadIdx.x >> 6;
  const int quad = lane >> 4, l15 = lane & 15;
  const int wr = (wave >> 1) * 64, wc = (wave & 1) * 64;
  float k2v[4];
#pragma unroll
  for (int j = 0; j < 4; ++j) k2v[j] = k2[blockIdx.y * 128 + wc + j * 16 + l15];
#pragma unroll
  for (int i = 0; i < 4; ++i)
#pragma unroll
    for (int r = 0; r < 4; ++r) {
      float v = -3.4e38f;
#pragma unroll
      for (int j = 0; j < 4; ++j) v = fmaxf(v, 2.f * acc[i][j][r] - k2v[j]);
      for (int m = 8; m; m >>= 1) v = fmaxf(v, __shfl_xor(v, m));
      if (l15 == 0) {
        const int gm = blockIdx.x * 128 + wr + i * 16 + quad * 4 + r;
        atomicMax(&rowmax[gm], enc_f32(v));
      }
    }
}

// ---------------------------------------------------------------- strip scorer: A-resident in LDS
// Block = 64 q-rows x 4096-key strip. A (64x256 bf16, padded stride 264) staged once;
// B streams in BK=64 chunks (two bank-clean BK=32 sub-tiles) via global_load_lds.
// Threshold = seeded rowmax - MARGIN (static lower bound => superset guaranteed).
__global__ __launch_bounds__(256) void score_strip(const unsigned short* __restrict__ qbf,
                                                   const unsigned short* __restrict__ kbf,
                                                   const float* __restrict__ k2,
                                                   const unsigned* __restrict__ rowmax,
                                                   int* __restrict__ cnt,
                                                   unsigned* __restrict__ cand) {
  __shared__ __align__(16) unsigned short As[64 * 264];
  __shared__ __align__(16) unsigned short Bs[2 * 4096];
  __shared__ float thr_s[64];
  const int t = threadIdx.x;
  const int bm = blockIdx.x;
  const int key0 = blockIdx.y * 4096;
  // stage A once (row-major, padded to 264 shorts -> 2-way banks on frag reads)
#pragma unroll
  for (int ii = 0; ii < 8; ++ii) {
    const int chunk = ii * 256 + t;
    const int row = chunk >> 5, cir = chunk & 31;
    *(float4*)(As + row * 264 + cir * 8) =
        *(const float4*)(qbf + (size_t)(bm * 64 + row) * DKDIM + cir * 8);
  }
  if (t < 64) thr_s[t] = dec_f32(rowmax[bm * 64 + t]) - MARGIN;
  const int lane = t & 63, wave = t >> 6;
  const int quad = lane >> 4, l15 = lane & 15;
  const int kh = t >> 2, kc = t & 3;          // B staging: key-half row, k-chunk
  for (int kt = 0; kt < 32; ++kt) {           // 128-key tiles within strip
    f32x4 acc[4][2] = {};
    float k2v[2];
#pragma unroll
    for (int j = 0; j < 2; ++j)
      k2v[j] = k2[key0 + kt * 128 + wave * 32 + j * 16 + l15];
    for (int it = 0; it < 4; ++it) {          // BK=64 per barrier pair
      __syncthreads();
#pragma unroll
      for (int s2 = 0; s2 < 2; ++s2)
#pragma unroll
        for (int h = 0; h < 2; ++h)
          gld16(kbf + (size_t)(key0 + kt * 128 + h * 64 + kh) * DKDIM + it * 64 + s2 * 32 + kc * 8,
                Bs + s2 * 4096 + h * 2048 + t * 8);
      __syncthreads();
#pragma unroll
      for (int s2 = 0; s2 < 2; ++s2) {
        bf16x8 af[4], bfr[2];
#pragma unroll
        for (int i = 0; i < 4; ++i)
          af[i] = *(const bf16x8*)(As + (i * 16 + l15) * 264 + it * 64 + s2 * 32 + quad * 8);
#pragma unroll
        for (int j = 0; j < 2; ++j)
          bfr[j] = *(const bf16x8*)(Bs + s2 * 4096 + (wave * 32 + j * 16 + l15) * 32 + quad * 8);
#pragma unroll
        for (int i = 0; i < 4; ++i)
#pragma unroll
          for (int j = 0; j < 2; ++j)
            acc[i][j] = __builtin_amdgcn_mfma_f32_16x16x32_bf16(af[i], bfr[j], acc[i][j], 0, 0, 0);
      }
    }
    // epilogue: push-only (no barriers, no atomicsMax — seed bound suffices)
#pragma unroll
    for (int i = 0; i < 4; ++i)
#pragma unroll
      for (int r = 0; r < 4; ++r) {
        const int rl = i * 16 + quad * 4 + r;
        const float th = thr_s[rl];
        const int gm = bm * 64 + rl;
#pragma unroll
        for (int j = 0; j < 2; ++j) {
          const float s = 2.f * acc[i][j][r] - k2v[j];
          if (s >= th) {
            const int n = key0 + kt * 128 + wave * 32 + j * 16 + l15;
            const int pos = atomicAdd(&cnt[gm], 1);
            if (pos < CAPS) cand[(size_t)gm * CAPS + pos] = pack_cand(s, n);
          }
        }
      }
  }
}

// ---------------------------------------------------------------- exact 8-round recursion per row
__global__ __launch_bounds__(256) void knn_rounds(const float* __restrict__ qf,
                                                  const float* __restrict__ keys,
                                                  const float* __restrict__ k2,
                                                  const float* __restrict__ vals,
                                                  const int* __restrict__ cnt,
                                                  const unsigned* __restrict__ cand,
                                                  unsigned short* __restrict__ nearest) {
  __shared__ __align__(16) float qs[DKDIM];
  __shared__ unsigned cl[CAPS];
  __shared__ float red[256];
  __shared__ int   sidx[SURV];
  __shared__ float Ls[SURV];
  __shared__ float cs[SURV];
  __shared__ float Ws[SURV * KN];
  __shared__ int nsurv;
  const int row = blockIdx.x, t = threadIdx.x;
  const int C = min(cnt[row], CAPS);
  qs[t] = qf[(size_t)row * DKDIM + t];
  if (t == 0) nsurv = 0;
  float m = -3.4e38f;
  for (int i = t; i < C; i += 256) {
    const unsigned p = cand[(size_t)row * CAPS + i];
    cl[i] = p;
    m = fmaxf(m, cand_score(p));
  }
  red[t] = m;
  __syncthreads();
  for (int s = 128; s; s >>= 1) {
    if (t < s) red[t] = fmaxf(red[t], red[t + s]);
    __syncthreads();
  }
  const float th = red[0] - 14.0f;   // approx-score filter; >=12.8 true margin
  for (int i = t; i < C; i += 256) {
    if (cand_score(cl[i]) >= th) {
      const int p = atomicAdd(&nsurv, 1);
      if (p < SURV) sidx[p] = (int)(cl[i] & 32767u);
    }
  }
  if (t < SURV) cs[t] = 0.f;
  __syncthreads();
  const int S = min(nsurv, SURV);
  // exact fp32 logits (q2 dropped: softmax is shift-invariant)
  const int wv = t >> 6, ln = t & 63;
  for (int i = wv; i < S; i += 4) {
    const int n = sidx[i];
    const float4 kv = *(const float4*)(keys + (size_t)n * DKDIM + ln * 4);
    const float4 qv = *(const float4*)(qs + ln * 4);
    float d = kv.x * qv.x + kv.y * qv.y + kv.z * qv.z + kv.w * qv.w;
    for (int o = 32; o; o >>= 1) d += __shfl_down(d, o);
    if (ln == 0) Ls[i] = (2.f * d - k2[n]) / 0.1f;
  }
  __syncthreads();
  if (t < 64) {  // wave 0 runs the recursion (S is small)
    for (int j = 0; j < KN; ++j) {
      float lm = -3.4e38f;
      for (int i = t; i < S; i += 64) lm = fmaxf(lm, Ls[i] + cs[i]);
      for (int o = 32; o; o >>= 1) lm = fmaxf(lm, __shfl_xor(lm, o));
      float zs = 0.f;
      for (int i = t; i < S; i += 64) {
        const float e = expf(Ls[i] + cs[i] - lm);
        Ws[i * KN + j] = e; zs += e;
      }
      for (int o = 32; o; o >>= 1) zs += __shfl_xor(zs, o);
      const float Zi = 1.f / zs;
      for (int i = t; i < S; i += 64) {
        const float w = Ws[i * KN + j] * Zi;
        Ws[i * KN + j] = w;
        cs[i] += log1pf(1e-6f - w);
      }
    }
  }
  __syncthreads();
  // one pass over survivor vals rows for all 8 rounds
  float acc[KN] = {};
  for (int i = 0; i < S; ++i) {
    const float v = vals[(size_t)sidx[i] * DMDIM + t];
#pragma unroll
    for (int j = 0; j < KN; ++j) acc[j] += Ws[i * KN + j] * v;
  }
#pragma unroll
  for (int j = 0; j < KN; ++j)
    nearest[(size_t)row * FDIM + j * DMDIM + t] = f2bf(acc[j]);
}

// ---------------------------------------------------------------- out = nearest @ W_out^T + b_out
__global__ __launch_bounds__(256) void out_gemm(const unsigned short* __restrict__ nbf,
                                                const unsigned short* __restrict__ wbf,
                                                const float* __restrict__ bout,
                                                float* __restrict__ out) {
  __shared__ __align__(16) unsigned short As[4096];
  __shared__ __align__(16) unsigned short Bs[4096];
  f32x4 acc[4][4] = {};
  gemm_tile<FDIM>(nbf, wbf, blockIdx.x, blockIdx.y, As, Bs, acc);
  const int lane = threadIdx.x & 63, wave = threadIdx.x >> 6;
  const int quad = lane >> 4, l15 = lane & 15;
  const int wr = (wave >> 1) * 64, wc = (wave & 1) * 64;
#pragma unroll
  for (int i = 0; i < 4; ++i)
#pragma unroll
    for (int r = 0; r < 4; ++r) {
      const int gm = blockIdx.x * 128 + wr + i * 16 + quad * 4 + r;
#pragma unroll
      for (int j = 0; j < 4; ++j) {
        const int n = blockIdx.y * 128 + wc + j * 16 + l15;
        out[(size_t)gm * DDIM + n] = acc[i][j][r] + bout[n];
      }
    }
}

// ---------------------------------------------------------------- RMSNorm epilogue (in-place)
__global__ __launch_bounds__(256) void rmsnorm(float* __restrict__ out,
                                               const float* __restrict__ rmsw) {
  __shared__ float red[256];
  const int row = blockIdx.x, t = threadIdx.x;
  const float4 v = *(const float4*)(out + (size_t)row * DDIM + t * 4);
  red[t] = v.x * v.x + v.y * v.y + v.z * v.z + v.w * v.w;
  __syncthreads();
  for (int s = 128; s; s >>= 1) {
    if (t < s) red[t] += red[t + s];
    __syncthreads();
  }
  const float scale = rsqrtf(red[0] / (float)DDIM + 1e-6f);
  const float4 w = *(const float4*)(rmsw + t * 4);
  float4 o;
  o.x = v.x * scale * w.x; o.y = v.y * scale * w.y;
  o.z = v.z * scale * w.z; o.w = v.w * scale * w.w;
  *(float4*)(out + (size_t)row * DDIM + t * 4) = o;
}

extern "C" void kernel_launch(void* const* d_in, const int* in_sizes, int n_in,
                              void* d_out, int out_size, void* d_ws, size_t ws_size,
                              hipStream_t stream) {
  const float* x    = (const float*)d_in[0];
  const float* keys = (const float*)d_in[1];
  const float* vals = (const float*)d_in[2];
  const float* Win  = (const float*)d_in[3];
  const float* bin  = (const float*)d_in[4];
  const float* Wout = (const float*)d_in[5];
  const float* bout = (const float*)d_in[6];
  const float* rmsw = (const float*)d_in[7];
  float* out = (float*)d_out;
  char* ws = (char*)d_ws;

  // workspace layout (total ~52.6 MB)
  float*          q_f32   = (float*)(ws);                       // 4 MB
  unsigned short* q_bf    = (unsigned short*)(ws + 4194304);    // 2 MB
  unsigned short* k_bf    = (unsigned short*)(ws + 6291456);    // 16 MB (dead after score_strip)
  unsigned short* nearest = (unsigned short*)(ws + 6291456);    // 16 MB overlay on k_bf
  float*          k2      = (float*)(ws + 23068672);            // 128 KB
  unsigned*       rowmax  = (unsigned*)(ws + 23199744);         // 16 KB
  int*            cnt     = (int*)(ws + 23216128);              // 16 KB
  unsigned*       cand    = (unsigned*)(ws + 23232512);         // 24 MB (4096*1536*4)
  unsigned short* w_bf    = (unsigned short*)(ws + 48398336);   // 4 MB

  hipMemsetAsync(rowmax, 0, 32768, stream);  // rowmax + cnt (contiguous)

  prep_keys<<<NKEYS / 4, 256, 0, stream>>>(keys, k_bf, k2);
  cvt_bf16<<<(DDIM * FDIM / 4) / 256, 256, 0, stream>>>(Wout, w_bf, DDIM * FDIM / 4);
  qproj<<<dim3(ROWS / 64, DKDIM / 64), 256, 0, stream>>>(x, Win, bin, q_f32, q_bf);
  seed_max<<<dim3(ROWS / 128, 16), 256, 0, stream>>>(q_bf, k_bf, k2, rowmax);
  score_strip<<<dim3(ROWS / 64, NKEYS / 4096), 256, 0, stream>>>(q_bf, k_bf, k2, rowmax, cnt, cand);
  knn_rounds<<<ROWS, 256, 0, stream>>>(q_f32, keys, k2, vals, cnt, cand, nearest);
  out_gemm<<<dim3(ROWS / 128, DDIM / 128), 256, 0, stream>>>(nearest, w_bf, bout, out);
  rmsnorm<<<ROWS, 256, 0, stream>>>(out, rmsw);
}

// Round 5
// 501.965 us; speedup vs baseline: 1.0159x; 1.0159x over previous
//
#include <hip/hip_runtime.h>
#include <hip/hip_bf16.h>

// Problem constants
#define ROWS  4096      // B*T
#define DDIM  1024
#define DKDIM 256
#define NKEYS 32768
#define DMDIM 256
#define KN    8
#define FDIM  2048      // KN*DM
#define CAPS  1536      // pushed-candidate cap per row (measured ~540/row worst)
#define SURV  128       // refilter survivors (mean 49, max ~90)
#define MARGIN 16.0f    // s-units; required bound ~12.8 incl bf16 err

typedef float  f32x4  __attribute__((ext_vector_type(4)));
typedef __bf16 bf16x8 __attribute__((ext_vector_type(8)));

static __device__ __forceinline__ unsigned enc_f32(float f) {
  unsigned u = __float_as_uint(f);
  return u ^ ((unsigned)((int)u >> 31) | 0x80000000u);
}
static __device__ __forceinline__ float dec_f32(unsigned u) {
  unsigned b = (u & 0x80000000u) ? (u ^ 0x80000000u) : ~u;
  return __uint_as_float(b);
}
static __device__ __forceinline__ unsigned short f2bf(float f) {
  unsigned u = __float_as_uint(f);
  u += 0x7FFFu + ((u >> 16) & 1u);          // RNE truncate to bf16
  return (unsigned short)(u >> 16);
}
// pack candidate: score quantized (1/64 res) high, key id (15 bits) low
static __device__ __forceinline__ unsigned pack_cand(float s, int n) {
  float q = (s + 1024.f) * 64.f;
  int u = (int)q;
  u = u < 0 ? 0 : (u > 131071 ? 131071 : u);
  return ((unsigned)u << 15) | (unsigned)n;
}
static __device__ __forceinline__ float cand_score(unsigned p) {
  return (float)(p >> 15) * (1.f / 64.f) - 1024.f;
}
static __device__ __forceinline__ void gld16(const void* g, void* l) {
  __builtin_amdgcn_global_load_lds((const __attribute__((address_space(1))) void*)g,
                                   (__attribute__((address_space(3))) void*)l, 16, 0, 0);
}

// ---------------------------------------------------------------- fused prep:
// blocks [0,8192): keys->bf16 + k2 ; [8192,10240): Wout->bf16 ; [10240,10272): zero rowmax+cnt
__global__ __launch_bounds__(256) void prep_all(const float* __restrict__ keys,
                                                const float* __restrict__ Wout,
                                                unsigned short* __restrict__ kbf,
                                                float* __restrict__ k2,
                                                unsigned short* __restrict__ wbf,
                                                unsigned* __restrict__ rowmax) {
  const int b = blockIdx.x, t = threadIdx.x;
  if (b < 8192) {
    const int row = b * 4 + (t >> 6);
    const int ln  = t & 63;
    const float4 v = *(const float4*)(keys + (size_t)row * DKDIM + ln * 4);
    ushort4 o;
    o.x = f2bf(v.x); o.y = f2bf(v.y); o.z = f2bf(v.z); o.w = f2bf(v.w);
    *(ushort4*)(kbf + (size_t)row * DKDIM + ln * 4) = o;
    float ss = v.x*v.x + v.y*v.y + v.z*v.z + v.w*v.w;
    for (int off = 32; off; off >>= 1) ss += __shfl_down(ss, off);
    if (ln == 0) k2[row] = ss;
  } else if (b < 10240) {
    const int i = (b - 8192) * 256 + t;      // i < 524288 = DDIM*FDIM/4
    const float4 v = *(const float4*)(Wout + (size_t)i * 4);
    ushort4 o;
    o.x = f2bf(v.x); o.y = f2bf(v.y); o.z = f2bf(v.z); o.w = f2bf(v.w);
    *(ushort4*)(wbf + (size_t)i * 4) = o;
  } else {
    rowmax[(b - 10240) * 256 + t] = 0u;      // zeroes rowmax(4096) + cnt(4096)
  }
}

// ---------------------------------------------------------------- q = x @ W_in^T + b_in (fp32)
__global__ __launch_bounds__(256) void qproj(const float* __restrict__ x,
                                             const float* __restrict__ Win,
                                             const float* __restrict__ bin,
                                             float* __restrict__ qf,
                                             unsigned short* __restrict__ qbf) {
  __shared__ __align__(16) float As[64][68];
  __shared__ __align__(16) float Bs[64][68];
  const int bm = blockIdx.x, bn = blockIdx.y;
  const int t  = threadIdx.x;
  const int tx = t & 15, ty = t >> 4;
  float acc[4][4] = {};
  for (int ks = 0; ks < 16; ++ks) {
    __syncthreads();
    for (int l = t; l < 1024; l += 256) {
      const int row = l >> 4, kc = l & 15;
      *(float4*)(&As[row][kc * 4]) =
          *(const float4*)(x + (size_t)(bm * 64 + row) * DDIM + ks * 64 + kc * 4);
      *(float4*)(&Bs[row][kc * 4]) =
          *(const float4*)(Win + (size_t)(bn * 64 + row) * DDIM + ks * 64 + kc * 4);
    }
    __syncthreads();
    for (int kk = 0; kk < 64; kk += 4) {
      float4 av[4], bv[4];
#pragma unroll
      for (int i = 0; i < 4; ++i) av[i] = *(const float4*)(&As[ty * 4 + i][kk]);
#pragma unroll
      for (int j = 0; j < 4; ++j) bv[j] = *(const float4*)(&Bs[tx * 4 + j][kk]);
#pragma unroll
      for (int i = 0; i < 4; ++i)
#pragma unroll
        for (int j = 0; j < 4; ++j)
          acc[i][j] += av[i].x * bv[j].x + av[i].y * bv[j].y +
                       av[i].z * bv[j].z + av[i].w * bv[j].w;
    }
  }
#pragma unroll
  for (int i = 0; i < 4; ++i)
#pragma unroll
    for (int j = 0; j < 4; ++j) {
      const int m = bm * 64 + ty * 4 + i, n = bn * 64 + tx * 4 + j;
      const float q = acc[i][j] + bin[n];
      qf[(size_t)m * DKDIM + n] = q;
      qbf[(size_t)m * DKDIM + n] = f2bf(q);
    }
}

// ---------------------------------------------------------------- shared MFMA tile (m97 structure)
template <int KD>
static __device__ __forceinline__ void gemm_tile(const unsigned short* __restrict__ A,
                                                 const unsigned short* __restrict__ B,
                                                 int bm, int bn,
                                                 unsigned short* As, unsigned short* Bs,
                                                 f32x4 acc[4][4]) {
  const int tid  = threadIdx.x;
  const int lane = tid & 63, wave = tid >> 6;
  const int quad = lane >> 4, l15 = lane & 15;
  const int wr = (wave >> 1) * 64, wc = (wave & 1) * 64;
  const int srow = tid >> 2, skc = tid & 3;
  const unsigned short* gA = A + (size_t)(bm * 128 + srow) * KD + skc * 8;
  const unsigned short* gB = B + (size_t)(bn * 128 + srow) * KD + skc * 8;
  for (int ks = 0; ks < KD / 32; ++ks) {
    __syncthreads();
    gld16(gA + ks * 32,                     As + tid * 8);
    gld16(gA + (size_t)64 * KD + ks * 32,   As + 2048 + tid * 8);
    gld16(gB + ks * 32,                     Bs + tid * 8);
    gld16(gB + (size_t)64 * KD + ks * 32,   Bs + 2048 + tid * 8);
    __syncthreads();
    bf16x8 af[4], bfr[4];
#pragma unroll
    for (int i = 0; i < 4; ++i)
      af[i] = *(const bf16x8*)(As + (wr + i * 16 + l15) * 32 + quad * 8);
#pragma unroll
    for (int j = 0; j < 4; ++j)
      bfr[j] = *(const bf16x8*)(Bs + (wc + j * 16 + l15) * 32 + quad * 8);
#pragma unroll
    for (int i = 0; i < 4; ++i)
#pragma unroll
      for (int j = 0; j < 4; ++j)
        acc[i][j] = __builtin_amdgcn_mfma_f32_16x16x32_bf16(af[i], bfr[j], acc[i][j], 0, 0, 0);
  }
}

// ---------------------------------------------------------------- fused score + select (single pass)
// Pushes superset { s >= max(wave tile max, running global row max) - MARGIN }.
// Determinism: final refiltered set {s >= smax-14} is always inside any pushed set
// (th <= gmax-16 unconditionally), and the global-argmax key is always pushed.
__global__ __launch_bounds__(256) void score_select(const unsigned short* __restrict__ qbf,
                                                    const unsigned short* __restrict__ kbf,
                                                    const float* __restrict__ k2,
                                                    unsigned* __restrict__ rowmax,
                                                    int* __restrict__ cnt,
                                                    unsigned* __restrict__ cand) {
  __shared__ __align__(16) unsigned short As[4096];
  __shared__ __align__(16) unsigned short Bs[4096];
  f32x4 acc[4][4] = {};
  gemm_tile<DKDIM>(qbf, kbf, blockIdx.x, blockIdx.y, As, Bs, acc);
  const int t = threadIdx.x;
  const int lane = t & 63, wave = t >> 6;
  const int quad = lane >> 4, l15 = lane & 15;
  const int wr = (wave >> 1) * 64, wc = (wave & 1) * 64;
  float k2v[4];
#pragma unroll
  for (int j = 0; j < 4; ++j) k2v[j] = k2[blockIdx.y * 128 + wc + j * 16 + l15];
#pragma unroll
  for (int i = 0; i < 4; ++i)
#pragma unroll
    for (int r = 0; r < 4; ++r) {
      float s[4];
      float v = -3.4e38f;
#pragma unroll
      for (int j = 0; j < 4; ++j) {
        s[j] = 2.f * acc[i][j][r] - k2v[j];
        v = fmaxf(v, s[j]);
      }
      for (int m = 8; m; m >>= 1) v = fmaxf(v, __shfl_xor(v, m));  // 16-lane row max
      const int gm = blockIdx.x * 128 + wr + i * 16 + quad * 4 + r;
      float th;
      if (l15 == 0) {
        const unsigned old = atomicMax(&rowmax[gm], enc_f32(v));
        th = fmaxf(v, dec_f32(old)) - MARGIN;   // dec(0-init)=NaN; fmaxf drops it
      }
      th = __shfl(th, lane & 48);               // broadcast from l15==0 of this quad
#pragma unroll
      for (int j = 0; j < 4; ++j) {
        if (s[j] >= th) {
          const int n = blockIdx.y * 128 + wc + j * 16 + l15;
          const int pos = atomicAdd(&cnt[gm], 1);
          if (pos < CAPS) cand[(size_t)gm * CAPS + pos] = pack_cand(s[j], n);
        }
      }
    }
}

// ---------------------------------------------------------------- exact 8-round recursion per row
__global__ __launch_bounds__(256) void knn_rounds(const float* __restrict__ qf,
                                                  const float* __restrict__ keys,
                                                  const float* __restrict__ k2,
                                                  const float* __restrict__ vals,
                                                  const int* __restrict__ cnt,
                                                  const unsigned* __restrict__ cand,
                                                  unsigned short* __restrict__ nearest) {
  __shared__ __align__(16) float qs[DKDIM];
  __shared__ unsigned cl[CAPS];
  __shared__ float red[256];
  __shared__ int   sidx[SURV];
  __shared__ float Ls[SURV];
  __shared__ float cs[SURV];
  __shared__ float Ws[SURV * KN];
  __shared__ int nsurv;
  const int row = blockIdx.x, t = threadIdx.x;
  const int C = min(cnt[row], CAPS);
  qs[t] = qf[(size_t)row * DKDIM + t];
  if (t == 0) nsurv = 0;
  float m = -3.4e38f;
  for (int i = t; i < C; i += 256) {
    const unsigned p = cand[(size_t)row * CAPS + i];
    cl[i] = p;
    m = fmaxf(m, cand_score(p));
  }
  red[t] = m;
  __syncthreads();
  for (int s = 128; s; s >>= 1) {
    if (t < s) red[t] = fmaxf(red[t], red[t + s]);
    __syncthreads();
  }
  const float th = red[0] - 14.0f;   // approx-score filter; >=12.8 true margin
  for (int i = t; i < C; i += 256) {
    if (cand_score(cl[i]) >= th) {
      const int p = atomicAdd(&nsurv, 1);
      if (p < SURV) sidx[p] = (int)(cl[i] & 32767u);
    }
  }
  if (t < SURV) cs[t] = 0.f;
  __syncthreads();
  const int S = min(nsurv, SURV);
  // exact fp32 logits (q2 dropped: softmax is shift-invariant)
  const int wv = t >> 6, ln = t & 63;
  for (int i = wv; i < S; i += 4) {
    const int n = sidx[i];
    const float4 kv = *(const float4*)(keys + (size_t)n * DKDIM + ln * 4);
    const float4 qv = *(const float4*)(qs + ln * 4);
    float d = kv.x * qv.x + kv.y * qv.y + kv.z * qv.z + kv.w * qv.w;
    for (int o = 32; o; o >>= 1) d += __shfl_down(d, o);
    if (ln == 0) Ls[i] = (2.f * d - k2[n]) / 0.1f;
  }
  __syncthreads();
  if (t < 64) {  // wave 0 runs the recursion (S is small)
    for (int j = 0; j < KN; ++j) {
      float lm = -3.4e38f;
      for (int i = t; i < S; i += 64) lm = fmaxf(lm, Ls[i] + cs[i]);
      for (int o = 32; o; o >>= 1) lm = fmaxf(lm, __shfl_xor(lm, o));
      float zs = 0.f;
      for (int i = t; i < S; i += 64) {
        const float e = expf(Ls[i] + cs[i] - lm);
        Ws[i * KN + j] = e; zs += e;
      }
      for (int o = 32; o; o >>= 1) zs += __shfl_xor(zs, o);
      const float Zi = 1.f / zs;
      for (int i = t; i < S; i += 64) {
        const float w = Ws[i * KN + j] * Zi;
        Ws[i * KN + j] = w;
        cs[i] += log1pf(1e-6f - w);
      }
    }
  }
  __syncthreads();
  // one pass over survivor vals rows for all 8 rounds
  float acc[KN] = {};
  for (int i = 0; i < S; ++i) {
    const float v = vals[(size_t)sidx[i] * DMDIM + t];
#pragma unroll
    for (int j = 0; j < KN; ++j) acc[j] += Ws[i * KN + j] * v;
  }
#pragma unroll
  for (int j = 0; j < KN; ++j)
    nearest[(size_t)row * FDIM + j * DMDIM + t] = f2bf(acc[j]);
}

// ---------------------------------------------------------------- out = nearest @ W_out^T + b_out
__global__ __launch_bounds__(256) void out_gemm(const unsigned short* __restrict__ nbf,
                                                const unsigned short* __restrict__ wbf,
                                                const float* __restrict__ bout,
                                                float* __restrict__ out) {
  __shared__ __align__(16) unsigned short As[4096];
  __shared__ __align__(16) unsigned short Bs[4096];
  f32x4 acc[4][4] = {};
  gemm_tile<FDIM>(nbf, wbf, blockIdx.x, blockIdx.y, As, Bs, acc);
  const int lane = threadIdx.x & 63, wave = threadIdx.x >> 6;
  const int quad = lane >> 4, l15 = lane & 15;
  const int wr = (wave >> 1) * 64, wc = (wave & 1) * 64;
#pragma unroll
  for (int i = 0; i < 4; ++i)
#pragma unroll
    for (int r = 0; r < 4; ++r) {
      const int gm = blockIdx.x * 128 + wr + i * 16 + quad * 4 + r;
#pragma unroll
      for (int j = 0; j < 4; ++j) {
        const int n = blockIdx.y * 128 + wc + j * 16 + l15;
        out[(size_t)gm * DDIM + n] = acc[i][j][r] + bout[n];
      }
    }
}

// ---------------------------------------------------------------- RMSNorm epilogue (in-place)
__global__ __launch_bounds__(256) void rmsnorm(float* __restrict__ out,
                                               const float* __restrict__ rmsw) {
  __shared__ float red[256];
  const int row = blockIdx.x, t = threadIdx.x;
  const float4 v = *(const float4*)(out + (size_t)row * DDIM + t * 4);
  red[t] = v.x * v.x + v.y * v.y + v.z * v.z + v.w * v.w;
  __syncthreads();
  for (int s = 128; s; s >>= 1) {
    if (t < s) red[t] += red[t + s];
    __syncthreads();
  }
  const float scale = rsqrtf(red[0] / (float)DDIM + 1e-6f);
  const float4 w = *(const float4*)(rmsw + t * 4);
  float4 o;
  o.x = v.x * scale * w.x; o.y = v.y * scale * w.y;
  o.z = v.z * scale * w.z; o.w = v.w * scale * w.w;
  *(float4*)(out + (size_t)row * DDIM + t * 4) = o;
}

extern "C" void kernel_launch(void* const* d_in, const int* in_sizes, int n_in,
                              void* d_out, int out_size, void* d_ws, size_t ws_size,
                              hipStream_t stream) {
  const float* x    = (const float*)d_in[0];
  const float* keys = (const float*)d_in[1];
  const float* vals = (const float*)d_in[2];
  const float* Win  = (const float*)d_in[3];
  const float* bin  = (const float*)d_in[4];
  const float* Wout = (const float*)d_in[5];
  const float* bout = (const float*)d_in[6];
  const float* rmsw = (const float*)d_in[7];
  float* out = (float*)d_out;
  char* ws = (char*)d_ws;

  // workspace layout (total ~52.6 MB)
  float*          q_f32   = (float*)(ws);                       // 4 MB
  unsigned short* q_bf    = (unsigned short*)(ws + 4194304);    // 2 MB
  unsigned short* k_bf    = (unsigned short*)(ws + 6291456);    // 16 MB (dead after score_select)
  unsigned short* nearest = (unsigned short*)(ws + 6291456);    // 16 MB overlay on k_bf
  float*          k2      = (float*)(ws + 23068672);            // 128 KB
  unsigned*       rowmax  = (unsigned*)(ws + 23199744);         // 16 KB
  int*            cnt     = (int*)(ws + 23216128);              // 16 KB (contiguous after rowmax)
  unsigned*       cand    = (unsigned*)(ws + 23232512);         // 24 MB (4096*1536*4)
  unsigned short* w_bf    = (unsigned short*)(ws + 48398336);   // 4 MB

  prep_all<<<10272, 256, 0, stream>>>(keys, Wout, k_bf, k2, w_bf, rowmax);
  qproj<<<dim3(ROWS / 64, DKDIM / 64), 256, 0, stream>>>(x, Win, bin, q_f32, q_bf);
  score_select<<<dim3(ROWS / 128, NKEYS / 128), 256, 0, stream>>>(q_bf, k_bf, k2, rowmax, cnt, cand);
  knn_rounds<<<ROWS, 256, 0, stream>>>(q_f32, keys, k2, vals, cnt, cand, nearest);
  out_gemm<<<dim3(ROWS / 128, DDIM / 128), 256, 0, stream>>>(nearest, w_bf, bout, out);
  rmsnorm<<<ROWS, 256, 0, stream>>>(out, rmsw);
}

// Round 6
// 438.471 us; speedup vs baseline: 1.1630x; 1.1448x over previous
//
#include <hip/hip_runtime.h>
#include <hip/hip_bf16.h>

// Problem constants
#define ROWS  4096      // B*T
#define DDIM  1024
#define DKDIM 256
#define NKEYS 32768
#define DMDIM 256
#define KN    8
#define FDIM  2048      // KN*DM
#define CAPS  1536      // pushed-candidate cap per row (measured ~540/row)
#define SURV  128       // stage-1 survivors (mean ~30 at 12.25, max << 128)
#define SURV2 96        // stage-2 survivors (mean ~21)
#define MARGIN   16.0f  // push margin, s-units (proven R2 value)
#define REFILT_M 12.25f // stage-1: 10.82 exact depth + 1.2 bf16 err + 0.05 quant
#define EXACT_M  109.0f // stage-2, logit units: 7*13.8 + ln(1e5)

typedef float  f32x4  __attribute__((ext_vector_type(4)));
typedef __bf16 bf16x8 __attribute__((ext_vector_type(8)));

static __device__ __forceinline__ unsigned enc_f32(float f) {
  unsigned u = __float_as_uint(f);
  return u ^ ((unsigned)((int)u >> 31) | 0x80000000u);
}
static __device__ __forceinline__ float dec_f32(unsigned u) {
  unsigned b = (u & 0x80000000u) ? (u ^ 0x80000000u) : ~u;
  return __uint_as_float(b);
}
static __device__ __forceinline__ unsigned short f2bf(float f) {
  unsigned u = __float_as_uint(f);
  u += 0x7FFFu + ((u >> 16) & 1u);          // RNE truncate to bf16
  return (unsigned short)(u >> 16);
}
// pack candidate: score quantized (1/64 res) high, key id (15 bits) low
static __device__ __forceinline__ unsigned pack_cand(float s, int n) {
  float q = (s + 1024.f) * 64.f;
  int u = (int)q;
  u = u < 0 ? 0 : (u > 131071 ? 131071 : u);
  return ((unsigned)u << 15) | (unsigned)n;
}
static __device__ __forceinline__ float cand_score(unsigned p) {
  return (float)(p >> 15) * (1.f / 64.f) - 1024.f;
}
static __device__ __forceinline__ void gld16(const void* g, void* l) {
  __builtin_amdgcn_global_load_lds((const __attribute__((address_space(1))) void*)g,
                                   (__attribute__((address_space(3))) void*)l, 16, 0, 0);
}

// ---------------------------------------------------------------- fused prep:
// blocks [0,8192): keys->bf16 + k2 ; [8192,10240): Wout->bf16 ; [10240,10272): zero rowmax+cnt
__global__ __launch_bounds__(256) void prep_all(const float* __restrict__ keys,
                                                const float* __restrict__ Wout,
                                                unsigned short* __restrict__ kbf,
                                                float* __restrict__ k2,
                                                unsigned short* __restrict__ wbf,
                                                unsigned* __restrict__ rowmax) {
  const int b = blockIdx.x, t = threadIdx.x;
  if (b < 8192) {
    const int row = b * 4 + (t >> 6);
    const int ln  = t & 63;
    const float4 v = *(const float4*)(keys + (size_t)row * DKDIM + ln * 4);
    ushort4 o;
    o.x = f2bf(v.x); o.y = f2bf(v.y); o.z = f2bf(v.z); o.w = f2bf(v.w);
    *(ushort4*)(kbf + (size_t)row * DKDIM + ln * 4) = o;
    float ss = v.x*v.x + v.y*v.y + v.z*v.z + v.w*v.w;
    for (int off = 32; off; off >>= 1) ss += __shfl_down(ss, off);
    if (ln == 0) k2[row] = ss;
  } else if (b < 10240) {
    const int i = (b - 8192) * 256 + t;      // i < 524288 = DDIM*FDIM/4
    const float4 v = *(const float4*)(Wout + (size_t)i * 4);
    ushort4 o;
    o.x = f2bf(v.x); o.y = f2bf(v.y); o.z = f2bf(v.z); o.w = f2bf(v.w);
    *(ushort4*)(wbf + (size_t)i * 4) = o;
  } else {
    rowmax[(b - 10240) * 256 + t] = 0u;      // zeroes rowmax(4096) + cnt(4096)
  }
}

// ---------------------------------------------------------------- q = x @ W_in^T + b_in (fp32)
__global__ __launch_bounds__(256) void qproj(const float* __restrict__ x,
                                             const float* __restrict__ Win,
                                             const float* __restrict__ bin,
                                             float* __restrict__ qf,
                                             unsigned short* __restrict__ qbf) {
  __shared__ __align__(16) float As[64][68];
  __shared__ __align__(16) float Bs[64][68];
  const int bm = blockIdx.x, bn = blockIdx.y;
  const int t  = threadIdx.x;
  const int tx = t & 15, ty = t >> 4;
  float acc[4][4] = {};
  for (int ks = 0; ks < 16; ++ks) {
    __syncthreads();
    for (int l = t; l < 1024; l += 256) {
      const int row = l >> 4, kc = l & 15;
      *(float4*)(&As[row][kc * 4]) =
          *(const float4*)(x + (size_t)(bm * 64 + row) * DDIM + ks * 64 + kc * 4);
      *(float4*)(&Bs[row][kc * 4]) =
          *(const float4*)(Win + (size_t)(bn * 64 + row) * DDIM + ks * 64 + kc * 4);
    }
    __syncthreads();
    for (int kk = 0; kk < 64; kk += 4) {
      float4 av[4], bv[4];
#pragma unroll
      for (int i = 0; i < 4; ++i) av[i] = *(const float4*)(&As[ty * 4 + i][kk]);
#pragma unroll
      for (int j = 0; j < 4; ++j) bv[j] = *(const float4*)(&Bs[tx * 4 + j][kk]);
#pragma unroll
      for (int i = 0; i < 4; ++i)
#pragma unroll
        for (int j = 0; j < 4; ++j)
          acc[i][j] += av[i].x * bv[j].x + av[i].y * bv[j].y +
                       av[i].z * bv[j].z + av[i].w * bv[j].w;
    }
  }
#pragma unroll
  for (int i = 0; i < 4; ++i)
#pragma unroll
    for (int j = 0; j < 4; ++j) {
      const int m = bm * 64 + ty * 4 + i, n = bn * 64 + tx * 4 + j;
      const float q = acc[i][j] + bin[n];
      qf[(size_t)m * DKDIM + n] = q;
      qbf[(size_t)m * DKDIM + n] = f2bf(q);
    }
}

// ---------------------------------------------------------------- shared MFMA tile (m97 structure)
template <int KD>
static __device__ __forceinline__ void gemm_tile(const unsigned short* __restrict__ A,
                                                 const unsigned short* __restrict__ B,
                                                 int bm, int bn,
                                                 unsigned short* As, unsigned short* Bs,
                                                 f32x4 acc[4][4]) {
  const int tid  = threadIdx.x;
  const int lane = tid & 63, wave = tid >> 6;
  const int quad = lane >> 4, l15 = lane & 15;
  const int wr = (wave >> 1) * 64, wc = (wave & 1) * 64;
  const int srow = tid >> 2, skc = tid & 3;
  const unsigned short* gA = A + (size_t)(bm * 128 + srow) * KD + skc * 8;
  const unsigned short* gB = B + (size_t)(bn * 128 + srow) * KD + skc * 8;
  for (int ks = 0; ks < KD / 32; ++ks) {
    __syncthreads();
    gld16(gA + ks * 32,                     As + tid * 8);
    gld16(gA + (size_t)64 * KD + ks * 32,   As + 2048 + tid * 8);
    gld16(gB + ks * 32,                     Bs + tid * 8);
    gld16(gB + (size_t)64 * KD + ks * 32,   Bs + 2048 + tid * 8);
    __syncthreads();
    bf16x8 af[4], bfr[4];
#pragma unroll
    for (int i = 0; i < 4; ++i)
      af[i] = *(const bf16x8*)(As + (wr + i * 16 + l15) * 32 + quad * 8);
#pragma unroll
    for (int j = 0; j < 4; ++j)
      bfr[j] = *(const bf16x8*)(Bs + (wc + j * 16 + l15) * 32 + quad * 8);
#pragma unroll
    for (int i = 0; i < 4; ++i)
#pragma unroll
      for (int j = 0; j < 4; ++j)
        acc[i][j] = __builtin_amdgcn_mfma_f32_16x16x32_bf16(af[i], bfr[j], acc[i][j], 0, 0, 0);
  }
}

// ---------------------------------------------------------------- fused score + select (R2 epilogue)
// Block-synchronized threshold: both wave-halves merged in LDS (full 128-key tile max),
// single atomicMax+readback per row AFTER the barrier. Proven 156 us (R2/R5 A/B showed
// per-wave thresholds quadruple the push count).
__global__ __launch_bounds__(256) void score_select(const unsigned short* __restrict__ qbf,
                                                    const unsigned short* __restrict__ kbf,
                                                    const float* __restrict__ k2,
                                                    unsigned* __restrict__ rowmax,
                                                    int* __restrict__ cnt,
                                                    unsigned* __restrict__ cand) {
  __shared__ __align__(16) unsigned short As[4096];
  __shared__ __align__(16) unsigned short Bs[4096];
  __shared__ float wm[128][2];
  __shared__ float thr[128];
  f32x4 acc[4][4] = {};
  gemm_tile<DKDIM>(qbf, kbf, blockIdx.x, blockIdx.y, As, Bs, acc);
  const int t = threadIdx.x;
  const int lane = t & 63, wave = t >> 6;
  const int quad = lane >> 4, l15 = lane & 15;
  const int wr = (wave >> 1) * 64, wc = (wave & 1) * 64;
  float k2v[4];
#pragma unroll
  for (int j = 0; j < 4; ++j) k2v[j] = k2[blockIdx.y * 128 + wc + j * 16 + l15];
  // per-wave row maxes -> LDS
#pragma unroll
  for (int i = 0; i < 4; ++i)
#pragma unroll
    for (int r = 0; r < 4; ++r) {
      float v = -3.4e38f;
#pragma unroll
      for (int j = 0; j < 4; ++j) v = fmaxf(v, 2.f * acc[i][j][r] - k2v[j]);
      for (int m = 8; m; m >>= 1) v = fmaxf(v, __shfl_xor(v, m));
      if (l15 == 0) wm[wr + i * 16 + quad * 4 + r][wave & 1] = v;
    }
  __syncthreads();
  if (t < 128) {
    const float tile = fmaxf(wm[t][0], wm[t][1]);
    const unsigned old = atomicMax(&rowmax[blockIdx.x * 128 + t], enc_f32(tile));
    thr[t] = fmaxf(tile, dec_f32(old)) - MARGIN;   // dec(0-init)=NaN; fmaxf drops it
  }
  __syncthreads();
#pragma unroll
  for (int i = 0; i < 4; ++i)
#pragma unroll
    for (int r = 0; r < 4; ++r) {
      const int rl = wr + i * 16 + quad * 4 + r;
      const float th = thr[rl];
      const int gm = blockIdx.x * 128 + rl;
#pragma unroll
      for (int j = 0; j < 4; ++j) {
        const float s = 2.f * acc[i][j][r] - k2v[j];
        if (s >= th) {
          const int n = blockIdx.y * 128 + wc + j * 16 + l15;
          const int pos = atomicAdd(&cnt[gm], 1);
          if (pos < CAPS) cand[(size_t)gm * CAPS + pos] = pack_cand(s, n);
        }
      }
    }
}

// ---------------------------------------------------------------- two-stage filter + exact recursion
__global__ __launch_bounds__(256) void knn_rounds(const float* __restrict__ qf,
                                                  const float* __restrict__ keys,
                                                  const float* __restrict__ k2,
                                                  const float* __restrict__ vals,
                                                  const int* __restrict__ cnt,
                                                  const unsigned* __restrict__ cand,
                                                  unsigned short* __restrict__ nearest) {
  __shared__ __align__(16) float qs[DKDIM];
  __shared__ unsigned cl[CAPS];
  __shared__ float red[256];
  __shared__ int   sidx[SURV];
  __shared__ float Ls[SURV];
  __shared__ int   sidx2[SURV2];
  __shared__ float L2v[SURV2];
  __shared__ float cs[SURV2];
  __shared__ float Ws[SURV2 * KN];
  __shared__ int n1, n2;
  const int row = blockIdx.x, t = threadIdx.x;
  const int C = min(cnt[row], CAPS);
  qs[t] = qf[(size_t)row * DKDIM + t];
  if (t == 0) { n1 = 0; n2 = 0; }
  float m = -3.4e38f;
  for (int i = t; i < C; i += 256) {
    const unsigned p = cand[(size_t)row * CAPS + i];
    cl[i] = p;
    m = fmaxf(m, cand_score(p));
  }
  red[t] = m;
  __syncthreads();
  for (int s = 128; s; s >>= 1) {
    if (t < s) red[t] = fmaxf(red[t], red[t + s]);
    __syncthreads();
  }
  // stage 1: approx-score filter (deterministic set; cap proven unreachable)
  const float th1 = red[0] - REFILT_M;
  for (int i = t; i < C; i += 256) {
    if (cand_score(cl[i]) >= th1) {
      const int p = atomicAdd(&n1, 1);
      if (p < SURV) sidx[p] = (int)(cl[i] & 32767u);
    }
  }
  if (t < SURV2) cs[t] = 0.f;
  __syncthreads();
  const int S1 = min(n1, SURV);
  // exact fp32 logits for stage-1 survivors (q2 dropped: softmax shift-invariant)
  const int wv = t >> 6, ln = t & 63;
  for (int i = wv; i < S1; i += 4) {
    const int n = sidx[i];
    const float4 kv = *(const float4*)(keys + (size_t)n * DKDIM + ln * 4);
    const float4 qv = *(const float4*)(qs + ln * 4);
    float d = kv.x * qv.x + kv.y * qv.y + kv.z * qv.z + kv.w * qv.w;
    for (int o = 32; o; o >>= 1) d += __shfl_down(d, o);
    if (ln == 0) Ls[i] = (2.f * d - k2[n]) / 0.1f;
  }
  __syncthreads();
  red[t] = (t < S1) ? Ls[t] : -3.4e38f;
  __syncthreads();
  for (int s = 128; s; s >>= 1) {
    if (t < s) red[t] = fmaxf(red[t], red[t + s]);
    __syncthreads();
  }
  // stage 2: exact-logit filter at rigorous depth
  const float Lmax = red[0];
  if (t < S1 && Ls[t] >= Lmax - EXACT_M) {
    const int p = atomicAdd(&n2, 1);
    if (p < SURV2) { sidx2[p] = sidx[t]; L2v[p] = Ls[t]; }
  }
  __syncthreads();
  const int S2 = min(n2, SURV2);
  if (t < 64) {  // wave 0 runs the recursion (S2 small)
    for (int j = 0; j < KN; ++j) {
      float lm = -3.4e38f;
      for (int i = t; i < S2; i += 64) lm = fmaxf(lm, L2v[i] + cs[i]);
      for (int o = 32; o; o >>= 1) lm = fmaxf(lm, __shfl_xor(lm, o));
      float zs = 0.f;
      for (int i = t; i < S2; i += 64) {
        const float e = expf(L2v[i] + cs[i] - lm);
        Ws[i * KN + j] = e; zs += e;
      }
      for (int o = 32; o; o >>= 1) zs += __shfl_xor(zs, o);
      const float Zi = 1.f / zs;
      for (int i = t; i < S2; i += 64) {
        const float w = Ws[i * KN + j] * Zi;
        Ws[i * KN + j] = w;
        cs[i] += log1pf(1e-6f - w);
      }
    }
  }
  __syncthreads();
  // one pass over stage-2 vals rows for all 8 rounds
  float acc[KN] = {};
  for (int i = 0; i < S2; ++i) {
    const float v = vals[(size_t)sidx2[i] * DMDIM + t];
#pragma unroll
    for (int j = 0; j < KN; ++j) acc[j] += Ws[i * KN + j] * v;
  }
#pragma unroll
  for (int j = 0; j < KN; ++j)
    nearest[(size_t)row * FDIM + j * DMDIM + t] = f2bf(acc[j]);
}

// ---------------------------------------------------------------- out = nearest @ W_out^T + b_out
__global__ __launch_bounds__(256) void out_gemm(const unsigned short* __restrict__ nbf,
                                                const unsigned short* __restrict__ wbf,
                                                const float* __restrict__ bout,
                                                float* __restrict__ out) {
  __shared__ __align__(16) unsigned short As[4096];
  __shared__ __align__(16) unsigned short Bs[4096];
  f32x4 acc[4][4] = {};
  gemm_tile<FDIM>(nbf, wbf, blockIdx.x, blockIdx.y, As, Bs, acc);
  const int lane = threadIdx.x & 63, wave = threadIdx.x >> 6;
  const int quad = lane >> 4, l15 = lane & 15;
  const int wr = (wave >> 1) * 64, wc = (wave & 1) * 64;
#pragma unroll
  for (int i = 0; i < 4; ++i)
#pragma unroll
    for (int r = 0; r < 4; ++r) {
      const int gm = blockIdx.x * 128 + wr + i * 16 + quad * 4 + r;
#pragma unroll
      for (int j = 0; j < 4; ++j) {
        const int n = blockIdx.y * 128 + wc + j * 16 + l15;
        out[(size_t)gm * DDIM + n] = acc[i][j][r] + bout[n];
      }
    }
}

// ---------------------------------------------------------------- RMSNorm epilogue (in-place)
__global__ __launch_bounds__(256) void rmsnorm(float* __restrict__ out,
                                               const float* __restrict__ rmsw) {
  __shared__ float red[256];
  const int row = blockIdx.x, t = threadIdx.x;
  const float4 v = *(const float4*)(out + (size_t)row * DDIM + t * 4);
  red[t] = v.x * v.x + v.y * v.y + v.z * v.z + v.w * v.w;
  __syncthreads();
  for (int s = 128; s; s >>= 1) {
    if (t < s) red[t] += red[t + s];
    __syncthreads();
  }
  const float scale = rsqrtf(red[0] / (float)DDIM + 1e-6f);
  const float4 w = *(const float4*)(rmsw + t * 4);
  float4 o;
  o.x = v.x * scale * w.x; o.y = v.y * scale * w.y;
  o.z = v.z * scale * w.z; o.w = v.w * scale * w.w;
  *(float4*)(out + (size_t)row * DDIM + t * 4) = o;
}

extern "C" void kernel_launch(void* const* d_in, const int* in_sizes, int n_in,
                              void* d_out, int out_size, void* d_ws, size_t ws_size,
                              hipStream_t stream) {
  const float* x    = (const float*)d_in[0];
  const float* keys = (const float*)d_in[1];
  const float* vals = (const float*)d_in[2];
  const float* Win  = (const float*)d_in[3];
  const float* bin  = (const float*)d_in[4];
  const float* Wout = (const float*)d_in[5];
  const float* bout = (const float*)d_in[6];
  const float* rmsw = (const float*)d_in[7];
  float* out = (float*)d_out;
  char* ws = (char*)d_ws;

  // workspace layout (total ~52.6 MB)
  float*          q_f32   = (float*)(ws);                       // 4 MB
  unsigned short* q_bf    = (unsigned short*)(ws + 4194304);    // 2 MB
  unsigned short* k_bf    = (unsigned short*)(ws + 6291456);    // 16 MB (dead after score_select)
  unsigned short* nearest = (unsigned short*)(ws + 6291456);    // 16 MB overlay on k_bf
  float*          k2      = (float*)(ws + 23068672);            // 128 KB
  unsigned*       rowmax  = (unsigned*)(ws + 23199744);         // 16 KB
  int*            cnt     = (int*)(ws + 23216128);              // 16 KB (contiguous after rowmax)
  unsigned*       cand    = (unsigned*)(ws + 23232512);         // 24 MB (4096*1536*4)
  unsigned short* w_bf    = (unsigned short*)(ws + 48398336);   // 4 MB

  prep_all<<<10272, 256, 0, stream>>>(keys, Wout, k_bf, k2, w_bf, rowmax);
  qproj<<<dim3(ROWS / 64, DKDIM / 64), 256, 0, stream>>>(x, Win, bin, q_f32, q_bf);
  score_select<<<dim3(ROWS / 128, NKEYS / 128), 256, 0, stream>>>(q_bf, k_bf, k2, rowmax, cnt, cand);
  knn_rounds<<<ROWS, 256, 0, stream>>>(q_f32, keys, k2, vals, cnt, cand, nearest);
  out_gemm<<<dim3(ROWS / 128, DDIM / 128), 256, 0, stream>>>(nearest, w_bf, bout, out);
  rmsnorm<<<ROWS, 256, 0, stream>>>(out, rmsw);
}